// Round 15
// baseline (112.991 us; speedup 1.0000x reference)
//
#include <hip/hip_runtime.h>
#include <hip/hip_bf16.h>
#include <math.h>

// ---------------- problem constants ----------------
#define NB 4
#define NH 96
#define NW 96
#define ND 768
#define NPIX (NH*NW)          // 9216
#define RR 3
#define NK 49
#define NS 2                  // K-split: 2 x 384 (grid 1152)
#define KQ 384
#define DCC 32                // K per staged chunk
#define NCH 12                // KQ/DCC
#define TSX 16                // tile 16 wide
#define TSY 4                 //        4 tall (wave per row)
#define HLX 22                // halo 22 wide
#define HLY 10                // halo 10 tall
#define NVIS (HLX*HLY)        // 220
#define VPAD 224              // vis region padded to multiple of 32
#define NSLOT (VPAD+64)       // 288 (224 vis+dummy, 64 rubin)
#define LROW 40               // ushorts per slot (32 bf16 + 8 pad = 80B)
#define NPASS 9               // 288 slots * 8 lanes / 256 threads
#define TPX 65                // transpose row stride (floats) — conflict-free
#define TBASE 512             // transpose region base (floats)
#define TAU 0.1f
#define SCALE 0.03608439182435161f  // 1/sqrt(768)
#define UNI (1.0f/49.0f)

typedef float f32x4 __attribute__((ext_vector_type(4)));
typedef short bfx8 __attribute__((ext_vector_type(8)));

__device__ __forceinline__ unsigned pk2(float lo, float hi) {
  __hip_bfloat162 h = __float22bfloat162_rn(make_float2(lo, hi));  // v_cvt_pk_bf16_f32
  unsigned u; __builtin_memcpy(&u, &h, 4);
  return u;
}

// barrier that waits LDS ops only (no vmcnt drain)
#define BARRIER() do { asm volatile("s_waitcnt lgkmcnt(0)" ::: "memory"); \
                       __builtin_amdgcn_s_barrier(); } while (0)

// ws layout:
//   partL : float [ns][b][49][NPIX]   raw fp32 corr partials
//   partS : float [ns][b][2][NPIX]    (0: rubin ss, 1: vis ss)
//   invr, invv, dyl, dxl : float [b][NPIX]
//   gacc  : float [b][49][144]
// out: dra | ddec | conf_local | conf_global[4] | lw

// ---------------- kernel B: banded MFMA correlation, K-split partials ----------------
// Register-quantum note (r14 lesson, m69): waves/SIMD halve at unified regs
// {64,128,256}. 140 regs (r13/r14: 84 VGPR + 56 acc) -> 2 waves/SIMD -> 25%
// occupancy ceiling regardless of grid. This round: NO prefetch array (-36 regs),
// target <=128 unified -> 4 waves/SIMD. launch_bounds(256,4) = 128-reg cap.
// Spill signature: VGPR_Count==64 AND WRITE_SIZE >> 15 MB (r8/r11).
__global__ __launch_bounds__(256, 4) void corr_part(
    const float* __restrict__ rubin, const float* __restrict__ vis,
    float* __restrict__ partL, float* __restrict__ partS) {
  __shared__ __align__(16) unsigned short lds[NSLOT*LROW];  // 23,040 B
  float* ldsf = (float*)lds;
  const int tid = threadIdx.x;

  // ---- XCD-chunked swizzle over (b,tile); ns in blockIdx.y ----
  const int wg = blockIdx.x;                  // 0..575
  const int vs = (wg & 7) * 72 + (wg >> 3);   // bijective (576 = 8*72)
  const int b = vs / 144, t = vs % 144;
  const int tileY = t / 6, tileX = t % 6;
  const int ns = blockIdx.y;
  const int k0 = ns * KQ;

  const int g8 = tid >> 3, q = tid & 7;       // 32 slots/pass, 8 lanes/slot

  // ---- staging slot -> global element offset ----
  unsigned voff[NPASS];
  const int lws0 = g8*LROW + q*4;             // pass p: lws0 + p*32*LROW
  #pragma unroll
  for (int p = 0; p < NPASS; ++p) {
    const int s = p*32 + g8;
    unsigned pix = 0;
    if (p < 7) {                                 // vis halo (or dummy)
      const int vy = s / HLX, vx = s % HLX;
      const int gh = min(max(tileY*TSY + vy - RR, 0), NH-1);
      const int gw = min(max(tileX*TSX + vx - RR, 0), NW-1);
      pix = (unsigned)(b*NPIX + gh*NW + gw);
    } else {                                     // rubin
      const int ridx = s - VPAD;
      pix = (unsigned)(b*NPIX + (tileY*TSY + (ridx >> 4))*NW + tileX*TSX + (ridx & 15));
    }
    voff[p] = pix*ND + (unsigned)(k0 + q*4);
  }
  #define ACT(p) ((p) != 6 || g8 < 28)

  // ---- MFMA addressing: wave wv owns tile row wv ----
  const int lane = tid & 63, wv = tid >> 6;
  const int j15 = lane & 15, kq = lane >> 4;
  const int aOff = (VPAD + wv*TSX + j15)*LROW + kq*8;
  const int bO0 = j15*LROW + kq*8;
  const int bO1 = min(j15 + 16, HLX-1)*LROW + kq*8;

  f32x4 acc[7][2];
  #pragma unroll
  for (int dy = 0; dy < 7; ++dy) {
    acc[dy][0] = (f32x4){0.f,0.f,0.f,0.f};
    acc[dy][1] = (f32x4){0.f,0.f,0.f,0.f};
  }
  float ssq[NPASS];
  #pragma unroll
  for (int p = 0; p < NPASS; ++p) ssq[p] = 0.f;

  // ---- K-loop: fused load+cvt+write staging (no prefetch regs), then MFMA ----
  for (int ch = 0; ch < NCH; ++ch) {
    if (ch) BARRIER();            // prev chunk's MFMA readers done
    #pragma unroll
    for (int p = 0; p < NPASS; ++p) if (ACT(p)) {
      const float4 v = (p < 7) ? *(const float4*)(vis   + voff[p] + ch*DCC)
                               : *(const float4*)(rubin + voff[p] + ch*DCC);
      ssq[p] += v.x*v.x + v.y*v.y + v.z*v.z + v.w*v.w;
      *(uint2*)&lds[lws0 + p*32*LROW] = make_uint2(pk2(v.x,v.y), pk2(v.z,v.w));
    }
    BARRIER();
    const bfx8 A = *(const bfx8*)&lds[aOff];
    #pragma unroll
    for (int dy = 0; dy < 7; ++dy) {
      const int rbase = (wv + dy)*HLX*LROW;
      const bfx8 B0 = *(const bfx8*)&lds[rbase + bO0];
      const bfx8 B1 = *(const bfx8*)&lds[rbase + bO1];
      acc[dy][0] = __builtin_amdgcn_mfma_f32_16x16x32_bf16(A, B0, acc[dy][0], 0, 0, 0);
      acc[dy][1] = __builtin_amdgcn_mfma_f32_16x16x32_bf16(A, B1, acc[dy][1], 0, 0, 0);
    }
  }
  BARRIER();   // all MFMA LDS reads done before epilogue clobbers lds

  // ---- epilogue phase 1: per-slot sum-of-squares into ldsf[0..287] ----
  #pragma unroll
  for (int p = 0; p < NPASS; ++p) {
    float r = ACT(p) ? ssq[p] : 0.f;
    r += __shfl_xor(r, 1); r += __shfl_xor(r, 2); r += __shfl_xor(r, 4);
    if (q == 0 && ACT(p)) ldsf[p*32 + g8] = r;
  }
  BARRIER();

  // ---- epilogue phase 2: transpose C-fragments -> ldsf[TBASE + px*TPX + j] ----
  #pragma unroll
  for (int dy = 0; dy < 7; ++dy)
    #pragma unroll
    for (int h = 0; h < 2; ++h)
      #pragma unroll
      for (int r = 0; r < 4; ++r) {
        const int i = kq*4 + r;
        const int dxp3 = h ? (j15 + 16 - i) : (j15 - i);
        if (dxp3 >= 0 && dxp3 < 7)
          ldsf[TBASE + (wv*TSX + i)*TPX + dy*7 + dxp3] = acc[dy][h][r];
      }
  BARRIER();

  // ---- epilogue phase 3: write fp32 partials (coalesced plane writes) ----
  {
    const int px = lane, rr = px >> 4, cc = px & 15;
    const int n = (tileY*TSY + rr)*NW + tileX*TSX + cc;
    float* pL = partL + ((size_t)(ns*NB + b)*NK)*NPIX;
    const int jstart = wv*12 + (wv > 0 ? 1 : 0);       // 13,12,12,12 taps
    const int jcnt = (wv == 0) ? 13 : 12;
    #pragma unroll
    for (int jj = 0; jj < 13; ++jj)
      if (jj < jcnt) {
        const int j = jstart + jj;
        pL[(size_t)j*NPIX + n] = ldsf[TBASE + px*TPX + j];
      }
    if (wv == 0) {
      float* pS = partS + ((size_t)(ns*NB + b)*2)*NPIX;
      pS[n] = ldsf[VPAD + px];                                   // rubin ss partial
      pS[(size_t)NPIX + n] = ldsf[(rr+RR)*HLX + cc + RR];        // vis ss partial
    }
  }
}

// ---------------- kernel C0: reduce ss -> inverse norms ----------------
__global__ void norm_kernel(const float* __restrict__ partS, float* __restrict__ invr,
                            float* __restrict__ invv) {
  const int g = blockIdx.x*256 + threadIdx.x;
  const int b = g / NPIX, n = g % NPIX;
  float sr = 0.f, sv = 0.f;
  #pragma unroll
  for (int ns = 0; ns < NS; ++ns) {
    sr += partS[((size_t)(ns*NB + b)*2 + 0)*NPIX + n];
    sv += partS[((size_t)(ns*NB + b)*2 + 1)*NPIX + n];
  }
  invr[g] = 1.f / fmaxf(sqrtf(sr), 1e-6f);
  invv[g] = 1.f / fmaxf(sqrtf(sv), 1e-6f);
}

// ---------------- kernel C1: logits + local softmax + global partials ----------------
__global__ __launch_bounds__(256) void local_kernel(
    const float* __restrict__ partL, const float* __restrict__ invr,
    const float* __restrict__ invv, float* __restrict__ dyl, float* __restrict__ dxl,
    float* __restrict__ gacc, float* __restrict__ out) {
  const int g = blockIdx.x*256 + threadIdx.x;
  const int b = g / NPIX, n = g % NPIX;
  const int h = n / NW, w = n % NW;
  const float ir = invr[g] * (SCALE / TAU);
  float t[NK];
  #pragma unroll
  for (int jy = 0; jy < 7; ++jy) {
    #pragma unroll
    for (int jx = 0; jx < 7; ++jx) {
      const int j = jy*7 + jx;
      const float c = partL[((size_t)b*NK + j)*NPIX + n]
                    + partL[((size_t)(NB + b)*NK + j)*NPIX + n];
      const int hh = min(max(h + jy - RR, 0), NH-1);
      const int wc = min(max(w + jx - RR, 0), NW-1);
      t[j] = c * ir * invv[b*NPIX + hh*NW + wc];
    }
  }
  const int lane = threadIdx.x & 63;
  const int waveid = (blockIdx.x % 36)*4 + (threadIdx.x >> 6);
  #pragma unroll
  for (int j = 0; j < NK; ++j) {
    float red = t[j];
    #pragma unroll
    for (int m = 1; m < 64; m <<= 1) red += __shfl_xor(red, m);
    if (lane == 0) gacc[((size_t)b*NK + j)*144 + waveid] = red;
  }
  float mx = t[0];
  #pragma unroll
  for (int j = 1; j < NK; ++j) mx = fmaxf(mx, t[j]);
  float s = 0.f, sy = 0.f, sx = 0.f;
  #pragma unroll
  for (int jy = 0; jy < 7; ++jy)
    #pragma unroll
    for (int jx = 0; jx < 7; ++jx) {
      const float e = expf(t[jy*7+jx] - mx);
      s += e; sy += e*(float)(jy-RR); sx += e*(float)(jx-RR);
    }
  const float inv_s = 1.f / s;
  dyl[g] = sy * inv_s;
  dxl[g] = sx * inv_s;
  out[(size_t)2*NB*NPIX + g] = inv_s;                 // conf_local
  const float lw = fminf(fmaxf((inv_s - UNI)/(1.f-UNI), 0.f), 1.f);
  out[(size_t)3*NB*NPIX + 4 + g] = lw;                // lw
}

// ---------------- kernel E: global softmax (per-block recompute) + blend + smooth ----------------
__global__ __launch_bounds__(256) void smooth_global(
    const float* __restrict__ dyl, const float* __restrict__ dxl,
    const float* __restrict__ gacc, float* __restrict__ out,
    const int* __restrict__ hvisp, const int* __restrict__ wvisp) {
  __shared__ float sh[2];
  const int g = blockIdx.x*256 + threadIdx.x;
  const int b = g / NPIX, n = g % NPIX;
  const int h = n / NW, w = n % NW;

  if (threadIdx.x < 64) {
    const int k = threadIdx.x;
    float t = -1e30f;
    if (k < NK) {
      float ssum = 0.f;
      for (int i = 0; i < 144; ++i) ssum += gacc[((size_t)b*NK + k)*144 + i];
      t = ssum * (1.f / (float)NPIX);
    }
    float m = t;
    #pragma unroll
    for (int msk = 1; msk < 64; msk <<= 1) m = fmaxf(m, __shfl_xor(m, msk));
    const float e = (k < NK) ? expf(t - m) : 0.f;
    const float dyv = (k < NK) ? (float)(k/7 - RR) : 0.f;
    const float dxv = (k < NK) ? (float)(k%7 - RR) : 0.f;
    float s = e, sy = e*dyv, sx = e*dxv;
    #pragma unroll
    for (int msk = 1; msk < 64; msk <<= 1) {
      s  += __shfl_xor(s,  msk);
      sy += __shfl_xor(sy, msk);
      sx += __shfl_xor(sx, msk);
    }
    if (k == 0) {
      out[(size_t)3*NB*NPIX + b] = 1.f / s;   // conf_global
      sh[0] = sy / s;
      sh[1] = sx / s;
    }
  }
  __syncthreads();
  const float dyg = sh[0], dxg = sh[1];

  const float* conf = out + (size_t)2*NB*NPIX;
  float sy = 0.f, sx = 0.f;
  #pragma unroll
  for (int ddy = -1; ddy <= 1; ++ddy)
    #pragma unroll
    for (int ddx = -1; ddx <= 1; ++ddx) {
      const int hh = h + ddy, wc = w + ddx;
      if (hh >= 0 && hh < NH && wc >= 0 && wc < NW) {   // zero padding
        const int q2 = b*NPIX + hh*NW + wc;
        const float cf = conf[q2];
        const float lw = fminf(fmaxf((cf - UNI)/(1.f-UNI), 0.f), 1.f);
        sy += lw*dyl[q2] + (1.f-lw)*dyg;
        sx += lw*dxl[q2] + (1.f-lw)*dxg;
      }
    }
  const float skyy = (float)hvisp[0] * 0.1f / (float)NH;
  const float skyx = (float)wvisp[0] * 0.1f / (float)NW;
  out[g] = sx * (1.f/9.f) * skyx;                     // dra
  out[(size_t)NB*NPIX + g] = sy * (1.f/9.f) * skyy;   // ddec
}

// ---------------- host launch ----------------
extern "C" void kernel_launch(void* const* d_in, const int* in_sizes, int n_in,
                              void* d_out, int out_size, void* d_ws, size_t ws_size,
                              hipStream_t stream) {
  (void)in_sizes; (void)n_in; (void)out_size; (void)ws_size;
  const float* rubin = (const float*)d_in[0];
  const float* vis   = (const float*)d_in[1];
  const int* hvis = (const int*)d_in[4];
  const int* wvis = (const int*)d_in[5];
  float* out = (float*)d_out;

  float* partL = (float*)d_ws;                         // NS*NB*49*NPIX
  float* partS = partL + (size_t)NS*NB*NK*NPIX;        // NS*NB*2*NPIX
  float* invr  = partS + (size_t)NS*NB*2*NPIX;
  float* invv  = invr + (size_t)NB*NPIX;
  float* dyl   = invv + (size_t)NB*NPIX;
  float* dxl   = dyl  + (size_t)NB*NPIX;
  float* gacc  = dxl  + (size_t)NB*NPIX;               // NB*49*144

  corr_part<<<dim3(576, NS), 256, 0, stream>>>(rubin, vis, partL, partS);
  norm_kernel<<<dim3((NB*NPIX)/256), 256, 0, stream>>>(partS, invr, invv);
  local_kernel<<<dim3((NB*NPIX)/256), 256, 0, stream>>>(partL, invr, invv, dyl, dxl, gacc, out);
  smooth_global<<<dim3((NB*NPIX)/256), 256, 0, stream>>>(dyl, dxl, gacc, out, hvis, wvis);
}

// Round 16
// 65.472 us; speedup vs baseline: 1.7258x; 1.7258x over previous
//
#include <hip/hip_runtime.h>
#include <hip/hip_bf16.h>
#include <math.h>

// ---------------- problem constants ----------------
#define NB 4
#define NH 96
#define NW 96
#define ND 768
#define NPIX (NH*NW)          // 9216
#define RR 3
#define NK 49
#define DCC 32                // K per staged chunk
#define NCH 24                // 768/32 — full K per block (fused, NS=1)
#define TS 8                  // tile 8x8 pixels
#define HLX 16                // halo width (14 used + 2 pad)
#define HLY 14                // halo height
#define NVIS (HLX*HLY)        // 224 vis slots
#define RBASE 224             // rubin slots start (slot index)
#define NSLOT 288             // 224 vis + 64 rubin (= 9 exact passes)
#define LROW 40               // ushorts per slot (32 bf16 + 8 pad = 80B)
#define NPASS 9               // 288*8/256 — all lanes active every pass
#define TPX 65                // transpose row stride (floats)
#define TBASE 512             // transpose region base (floats)
#define PBASE 4672            // softmax partials base (floats); 4672+1024=5696<=5760
#define TAU 0.1f
#define SCALE 0.03608439182435161f  // 1/sqrt(768)
#define UNI (1.0f/49.0f)

typedef float f32x4 __attribute__((ext_vector_type(4)));
typedef short bfx8 __attribute__((ext_vector_type(8)));

__device__ __forceinline__ unsigned pk2(float lo, float hi) {
  __hip_bfloat162 h = __float22bfloat162_rn(make_float2(lo, hi));  // v_cvt_pk_bf16_f32
  unsigned u; __builtin_memcpy(&u, &h, 4);
  return u;
}

// barrier that waits LDS ops only (no vmcnt drain — prefetch stays in flight)
#define BARRIER() do { asm volatile("s_waitcnt lgkmcnt(0)" ::: "memory"); \
                       __builtin_amdgcn_s_barrier(); } while (0)

// ws layout: dyl, dxl : float [b][NPIX] ; gacc : float [b][49][144]
// out: dra | ddec | conf_local | conf_global[4] | lw

// ---------------- fused kernel: paired-row MFMA correlation + softmax ----------------
// MFMA scheme: 8x8 tile, wave wv owns rows {2wv, 2wv+1}. A-frag j<8 -> (row 2wv,
// x=j), j>=8 -> (row 2wv+1, x=j-8). One B-row fragment (16 cols, 14 used) covers
// the dx band of BOTH halves -> 8 MFMAs/chunk (B rows 2wv+m, m=0..7), each giving
// two dy taps: dy = m-3-(i>=8). acc = 8 f32x4 = 32 AGPRs (vs 56 in the 16x4 tile).
// Register quantum (m69): waves/SIMD halve at {64,128,256} unified. Target <=128
// -> 4 waves/SIMD. Spill signature: VGPR_Count==64 + WRITE_SIZE >> 1 MB.
__global__ __launch_bounds__(256, 4) void corr_fused(
    const float* __restrict__ rubin, const float* __restrict__ vis,
    float* __restrict__ dyl, float* __restrict__ dxl,
    float* __restrict__ gacc, float* __restrict__ out) {
  __shared__ __align__(16) unsigned short lds[NSLOT*LROW];  // 23,040 B (5760 floats)
  float* ldsf = (float*)lds;
  const int tid = threadIdx.x;

  // ---- XCD-chunked swizzle: 576 blocks = 8 XCD x 72 ----
  const int wg = blockIdx.x;
  const int vs = (wg & 7) * 72 + (wg >> 3);   // bijective
  const int b = vs / 144, t = vs % 144;       // 144 tiles (12x12) per batch
  const int tileY = t / 12, tileX = t % 12;

  const int g8 = tid >> 3, q = tid & 7;       // 32 slots/pass, 8 lanes/slot

  // ---- staging slot -> global element offset (p<7: vis halo, p>=7: rubin) ----
  unsigned voff[NPASS];
  const int lws0 = g8*LROW + q*4;             // pass p at lws0 + p*32*LROW
  #pragma unroll
  for (int p = 0; p < NPASS; ++p) {
    const int s = p*32 + g8;
    unsigned pix;
    if (p < 7) {                               // vis halo slot: hy=s>>4, hx=s&15
      const int hy = s >> 4, hx = s & 15;
      const int gh = min(max(tileY*TS + hy - RR, 0), NH-1);
      const int gw = min(max(tileX*TS + hx - RR, 0), NW-1);
      pix = (unsigned)(b*NPIX + gh*NW + gw);
    } else {                                   // rubin slot: ridx = s-224
      const int ridx = s - RBASE;
      pix = (unsigned)(b*NPIX + (tileY*TS + (ridx >> 3))*NW + tileX*TS + (ridx & 7));
    }
    voff[p] = pix*ND + (unsigned)(q*4);
  }

  // ---- MFMA addressing ----
  const int lane = tid & 63, wv = tid >> 6;
  const int j15 = lane & 15, kq = lane >> 4;
  const int aOff = (RBASE + wv*16 + j15)*LROW + kq*8;   // rubin rows 2wv,2wv+1
  const int bO = j15*LROW + kq*8;                        // + (2wv+m)*HLX*LROW

  f32x4 acc[8];
  #pragma unroll
  for (int m = 0; m < 8; ++m) acc[m] = (f32x4){0.f,0.f,0.f,0.f};
  float ssq[NPASS];
  #pragma unroll
  for (int p = 0; p < NPASS; ++p) ssq[p] = 0.f;

#define LOADCH(Larr, chv) { \
  _Pragma("unroll") \
  for (int p = 0; p < NPASS; ++p) \
    Larr[p] = (p < 7) ? *(const float4*)(vis   + voff[p] + (chv)*DCC) \
                      : *(const float4*)(rubin + voff[p] + (chv)*DCC); }

#define WRITECH(Larr) { \
  _Pragma("unroll") \
  for (int p = 0; p < NPASS; ++p) { \
    const float4 v = Larr[p]; \
    ssq[p] += v.x*v.x + v.y*v.y + v.z*v.z + v.w*v.w; \
    *(uint2*)&lds[lws0 + p*32*LROW] = make_uint2(pk2(v.x,v.y), pk2(v.z,v.w)); } }

  // ---- 1-deep software pipeline (r13 structure) ----
  float4 L[NPASS];
  LOADCH(L, 0);
  for (int ch = 0; ch < NCH; ++ch) {
    if (ch) BARRIER();            // prev chunk's MFMA readers done
    WRITECH(L);
    BARRIER();
    if (ch + 1 < NCH) LOADCH(L, ch + 1);   // in flight during MFMA + next barrier
    const bfx8 A = *(const bfx8*)&lds[aOff];
    #pragma unroll
    for (int m = 0; m < 8; ++m) {
      const bfx8 B = *(const bfx8*)&lds[(2*wv + m)*(HLX*LROW) + bO];
      acc[m] = __builtin_amdgcn_mfma_f32_16x16x32_bf16(A, B, acc[m], 0, 0, 0);
    }
  }
  BARRIER();   // all MFMA LDS reads done before epilogue clobbers lds

  // ---- epilogue phase 1: per-slot sum-of-squares into ldsf[0..287] ----
  #pragma unroll
  for (int p = 0; p < NPASS; ++p) {
    float r = ssq[p];
    r += __shfl_xor(r, 1); r += __shfl_xor(r, 2); r += __shfl_xor(r, 4);
    if (q == 0) ldsf[p*32 + g8] = r;
  }
  BARRIER();

  // ---- epilogue phase 2: scatter C-fragments -> ldsf[TBASE + px*TPX + tap] ----
  // C element (i=kq*4+r, col j15) of acc[m]: out pixel px = wv*16 + i,
  // dyp3 = m - (i>=8), dxp3 = j15 - (i&7).
  #pragma unroll
  for (int m = 0; m < 8; ++m)
    #pragma unroll
    for (int r = 0; r < 4; ++r) {
      const int i = kq*4 + r;
      const int dyp3 = m - (i >> 3);
      const int dxp3 = j15 - (i & 7);
      if (dyp3 >= 0 && dyp3 < 7 && dxp3 >= 0 && dxp3 < 7)
        ldsf[TBASE + (wv*16 + i)*TPX + dyp3*7 + dxp3] = acc[m][r];
    }
  BARRIER();

  // ---- epilogue phase 3: wave-parallel softmax (wave wv owns 12-13 taps) ----
  {
    const int px = lane;                       // transpose index 0..63
    const int ii = px & 15;
    const int rr = 2*(px >> 4) + (ii >> 3), cc = ii & 7;   // tile row/col (8x8)
    const float irf = (SCALE/TAU) / fmaxf(sqrtf(ldsf[RBASE + rr*8 + cc]), 1e-6f);
    const int jstart = wv*12 + (wv > 0 ? 1 : 0);           // 13,12,12,12 taps
    const int jcnt = (wv == 0) ? 13 : 12;
    float tvv[13];
    float mx = -1e30f;
    #pragma unroll
    for (int jj = 0; jj < 13; ++jj) {
      if (jj < jcnt) {
        const int j = jstart + jj;
        const int jy = j / 7, jx = j % 7;
        const float c = ldsf[TBASE + px*TPX + j];
        const float iv = 1.f / fmaxf(sqrtf(ldsf[(rr+jy)*HLX + cc + jx]), 1e-6f);
        const float tv = c * irf * iv;
        tvv[jj] = tv;
        mx = fmaxf(mx, tv);
        float red = tv;                                   // tile-sum for global softmax
        #pragma unroll
        for (int m = 1; m < 64; m <<= 1) red += __shfl_xor(red, m);
        if (lane == 0) gacc[((size_t)b*NK + j)*144 + t] = red;
      } else tvv[jj] = -1e30f;
    }
    float s = 0.f, sy = 0.f, sx = 0.f;
    #pragma unroll
    for (int jj = 0; jj < 13; ++jj) {
      if (jj < jcnt) {
        const int j = jstart + jj;
        const float e = expf(tvv[jj] - mx);
        s += e; sy += e*(float)(j/7 - RR); sx += e*(float)(j%7 - RR);
      }
    }
    float* pp = &ldsf[PBASE + (wv*64 + px)*4];
    pp[0] = mx; pp[1] = s; pp[2] = sy; pp[3] = sx;
  }
  BARRIER();

  // ---- epilogue phase 4: combine wave partials (wave 0), write outputs ----
  if (wv == 0) {
    const int px = lane;
    const int ii = px & 15;
    const int rr = 2*(px >> 4) + (ii >> 3), cc = ii & 7;
    float M[4], S[4], SY[4], SX[4];
    #pragma unroll
    for (int w = 0; w < 4; ++w) {
      const float* pp = &ldsf[PBASE + (w*64 + px)*4];
      M[w] = pp[0]; S[w] = pp[1]; SY[w] = pp[2]; SX[w] = pp[3];
    }
    float m = fmaxf(fmaxf(M[0], M[1]), fmaxf(M[2], M[3]));
    float s = 0.f, sy = 0.f, sx = 0.f;
    #pragma unroll
    for (int w = 0; w < 4; ++w) {
      const float f = expf(M[w] - m);
      s += S[w]*f; sy += SY[w]*f; sx += SX[w]*f;
    }
    const float inv_s = 1.f / s;
    const int n = (tileY*TS + rr)*NW + tileX*TS + cc;
    const int gg = b*NPIX + n;
    dyl[gg] = sy * inv_s;
    dxl[gg] = sx * inv_s;
    out[(size_t)2*NB*NPIX + gg] = inv_s;                       // conf_local
    const float lw = fminf(fmaxf((inv_s - UNI)/(1.f-UNI), 0.f), 1.f);
    out[(size_t)3*NB*NPIX + 4 + gg] = lw;                      // lw
  }
}

// ---------------- kernel E: global softmax (per-block recompute) + blend + smooth ----------------
__global__ __launch_bounds__(256) void smooth_global(
    const float* __restrict__ dyl, const float* __restrict__ dxl,
    const float* __restrict__ gacc, float* __restrict__ out,
    const int* __restrict__ hvisp, const int* __restrict__ wvisp) {
  __shared__ float sh[2];
  const int g = blockIdx.x*256 + threadIdx.x;
  const int b = g / NPIX, n = g % NPIX;
  const int h = n / NW, w = n % NW;

  if (threadIdx.x < 64) {
    const int k = threadIdx.x;
    float t = -1e30f;
    if (k < NK) {
      float ssum = 0.f;
      for (int i = 0; i < 144; ++i) ssum += gacc[((size_t)b*NK + k)*144 + i];
      t = ssum * (1.f / (float)NPIX);
    }
    float m = t;
    #pragma unroll
    for (int msk = 1; msk < 64; msk <<= 1) m = fmaxf(m, __shfl_xor(m, msk));
    const float e = (k < NK) ? expf(t - m) : 0.f;
    const float dyv = (k < NK) ? (float)(k/7 - RR) : 0.f;
    const float dxv = (k < NK) ? (float)(k%7 - RR) : 0.f;
    float s = e, sy = e*dyv, sx = e*dxv;
    #pragma unroll
    for (int msk = 1; msk < 64; msk <<= 1) {
      s  += __shfl_xor(s,  msk);
      sy += __shfl_xor(sy, msk);
      sx += __shfl_xor(sx, msk);
    }
    if (k == 0) {
      out[(size_t)3*NB*NPIX + b] = 1.f / s;   // conf_global
      sh[0] = sy / s;
      sh[1] = sx / s;
    }
  }
  __syncthreads();
  const float dyg = sh[0], dxg = sh[1];

  const float* conf = out + (size_t)2*NB*NPIX;
  float sy = 0.f, sx = 0.f;
  #pragma unroll
  for (int ddy = -1; ddy <= 1; ++ddy)
    #pragma unroll
    for (int ddx = -1; ddx <= 1; ++ddx) {
      const int hh = h + ddy, wc = w + ddx;
      if (hh >= 0 && hh < NH && wc >= 0 && wc < NW) {   // zero padding
        const int q2 = b*NPIX + hh*NW + wc;
        const float cf = conf[q2];
        const float lw = fminf(fmaxf((cf - UNI)/(1.f-UNI), 0.f), 1.f);
        sy += lw*dyl[q2] + (1.f-lw)*dyg;
        sx += lw*dxl[q2] + (1.f-lw)*dxg;
      }
    }
  const float skyy = (float)hvisp[0] * 0.1f / (float)NH;
  const float skyx = (float)wvisp[0] * 0.1f / (float)NW;
  out[g] = sx * (1.f/9.f) * skyx;                     // dra
  out[(size_t)NB*NPIX + g] = sy * (1.f/9.f) * skyy;   // ddec
}

// ---------------- host launch ----------------
extern "C" void kernel_launch(void* const* d_in, const int* in_sizes, int n_in,
                              void* d_out, int out_size, void* d_ws, size_t ws_size,
                              hipStream_t stream) {
  (void)in_sizes; (void)n_in; (void)out_size; (void)ws_size;
  const float* rubin = (const float*)d_in[0];
  const float* vis   = (const float*)d_in[1];
  const int* hvis = (const int*)d_in[4];
  const int* wvis = (const int*)d_in[5];
  float* out = (float*)d_out;

  float* dyl  = (float*)d_ws;                       // NB*NPIX
  float* dxl  = dyl  + (size_t)NB*NPIX;             // NB*NPIX
  float* gacc = dxl  + (size_t)NB*NPIX;             // NB*49*144

  corr_fused<<<dim3(576), 256, 0, stream>>>(rubin, vis, dyl, dxl, gacc, out);
  smooth_global<<<dim3((NB*NPIX)/256), 256, 0, stream>>>(dyl, dxl, gacc, out, hvis, wvis);
}